// Round 5
// baseline (3605.669 us; speedup 1.0000x reference)
//
#include <hip/hip_runtime.h>
#include <hip/hip_bf16.h>
#include <math.h>

#define BB 8
#define SS 1024
#define DD 768
#define HH 12
#define LL 6
#define FF 3072
#define CC 10
#define BS_ (BB * SS)   // 8192 rows

typedef __attribute__((ext_vector_type(8))) short short8v;       // bf16x8 MFMA frag
typedef __attribute__((ext_vector_type(4))) float f32x4;         // MFMA acc
typedef __attribute__((ext_vector_type(8))) unsigned short ushort8v;
typedef __attribute__((ext_vector_type(4))) unsigned short ushort4v;
typedef __attribute__((ext_vector_type(2))) unsigned int uint2v;

__device__ inline unsigned short f2bf(float f) {
  unsigned int u = __builtin_bit_cast(unsigned int, f);
  u += 0x7fffu + ((u >> 16) & 1u);
  return (unsigned short)(u >> 16);
}
__device__ inline float bf2f(unsigned short u) {
  return __builtin_bit_cast(float, (unsigned int)u << 16);
}
__device__ inline unsigned int pack_bf2(float lo, float hi) {
  unsigned int a = __builtin_bit_cast(unsigned int, lo);
  unsigned int b = __builtin_bit_cast(unsigned int, hi);
  a += 0x7fffu + ((a >> 16) & 1u);
  b += 0x7fffu + ((b >> 16) & 1u);
  return __builtin_amdgcn_perm(b, a, 0x07060302u);
}
__device__ inline void gload16(const void* g, void* l) {
  __builtin_amdgcn_global_load_lds((const __attribute__((address_space(1))) void*)g,
                                   (__attribute__((address_space(3))) void*)l, 16, 0, 0);
}

// ---------------- reduction helpers ----------------
__device__ inline float wave_sum(float v) {
#pragma unroll
  for (int off = 32; off > 0; off >>= 1) v += __shfl_down(v, off);
  return v;
}
__device__ inline float block_sum(float v, float* red) {
  int t = threadIdx.x;
  v = wave_sum(v);
  __syncthreads();
  if ((t & 63) == 0) red[t >> 6] = v;
  __syncthreads();
  return red[0] + red[1] + red[2] + red[3];
}

// ---------------- embedding + sinusoidal PE ----------------
__global__ __launch_bounds__(256) void k_embed(const int* __restrict__ tokens,
                                               const float* __restrict__ emb,
                                               float* __restrict__ x,
                                               ushort* __restrict__ xb) {
  int row = blockIdx.x;
  int s = row & (SS - 1);
  int tok = tokens[row];
  const float* e = emb + (size_t)tok * DD;
  float* xr = x + (size_t)row * DD;
  ushort* xbr = xb + (size_t)row * DD;
  for (int d = threadIdx.x; d < DD; d += 256) {
    float freq = expf((float)(d & ~1) * -0.0119926306f);
    float ang = (float)s * freq;
    float pe = (d & 1) ? cosf(ang) : sinf(ang);
    float v = e[d] + pe;
    xr[d] = v;
    xbr[d] = f2bf(v);
  }
}

// ---------------- fused per-layer weight transpose ----------------
__global__ __launch_bounds__(256) void k_transpose_all(
    const float* __restrict__ wq, const float* __restrict__ wk,
    const float* __restrict__ wv, const float* __restrict__ wo,
    const float* __restrict__ w1, const float* __restrict__ w2,
    ushort* __restrict__ wqkv_t, ushort* __restrict__ wo_t,
    ushort* __restrict__ w1_t, ushort* __restrict__ w2_t) {
  __shared__ float tile[32][33];
  int bid = blockIdx.x;
  const float* W; ushort* Wt; int K, N, lb;
  if (bid < 1728) {
    int m = bid / 576; lb = bid - m * 576;
    W = (m == 0) ? wq : (m == 1) ? wk : wv;
    Wt = wqkv_t + m * 768 * 768; K = 768; N = 768;
  } else if (bid < 2304) {
    W = wo; Wt = wo_t; K = 768; N = 768; lb = bid - 1728;
  } else if (bid < 4608) {
    W = w1; Wt = w1_t; K = 768; N = 3072; lb = bid - 2304;
  } else {
    W = w2; Wt = w2_t; K = 3072; N = 768; lb = bid - 4608;
  }
  int nbk = K >> 5;
  int k0 = (lb % nbk) * 32, n0 = (lb / nbk) * 32;
  int t = threadIdx.x;
  int r = t >> 3, c4 = (t & 7) * 4;
  float4 v = *(const float4*)(W + (size_t)(k0 + r) * N + n0 + c4);
  tile[r][c4 + 0] = v.x; tile[r][c4 + 1] = v.y;
  tile[r][c4 + 2] = v.z; tile[r][c4 + 3] = v.w;
  __syncthreads();
  ushort4v o;
#pragma unroll
  for (int i = 0; i < 4; ++i) o[i] = f2bf(tile[c4 + i][r]);
  *(ushort4v*)(Wt + (size_t)(n0 + r) * K + k0 + c4) = o;
}

// ---------------- flat bf16 MFMA GEMM (no LDS staging, no K-loop barriers) ----------------
// C[M,N](bf16) = A[M,K] @ Bt[N,K]^T. 128xTN tile, 4 waves.
// Fragments loaded directly from global (L2/L3-resident operands), 2-deep
// register pipeline. LDS used only for the coalesced bf16 epilogue.
template <int RELU, int TN>
__global__ __launch_bounds__(256) void k_gemm_flat(const ushort* __restrict__ A,
                                                   const ushort* __restrict__ Bt,
                                                   ushort* __restrict__ Cout,
                                                   int M, int N, int K) {
  constexpr int NI = TN / 64;            // B frags per wave (2 for TN=128, 1 for TN=64... see wc)
  __shared__ ushort cst[128 * TN];
  int n0 = blockIdx.x * TN, m0 = blockIdx.y * 128;
  int t = threadIdx.x, w = t >> 6, l = t & 63;
  int wr = (w >> 1) * 64;
  int wc = (w & 1) * (TN / 2);
  int lr = l & 15, lg = l >> 4;
  constexpr int NF = 2 * NI;             // 4 for TN=128, 2 for TN=64
  const ushort* ap = A + (size_t)(m0 + wr + lr) * K + lg * 8;
  const ushort* bp = Bt + (size_t)(n0 + wc + lr) * K + lg * 8;
  f32x4 acc[4][NF] = {};
  short8v a0[4], b0[NF], a1[4], b1[NF];
#pragma unroll
  for (int i = 0; i < 4; ++i) a0[i] = *(const short8v*)(ap + (size_t)i * 16 * K);
#pragma unroll
  for (int i = 0; i < NF; ++i) b0[i] = *(const short8v*)(bp + (size_t)i * 16 * K);
  int nk = K >> 5;
  for (int ki = 0; ki < nk; ki += 2) {
    {  // prefetch step ki+1 (nk is even, always valid)
      const ushort* ap1 = ap + (ki + 1) * 32;
      const ushort* bp1 = bp + (ki + 1) * 32;
#pragma unroll
      for (int i = 0; i < 4; ++i) a1[i] = *(const short8v*)(ap1 + (size_t)i * 16 * K);
#pragma unroll
      for (int i = 0; i < NF; ++i) b1[i] = *(const short8v*)(bp1 + (size_t)i * 16 * K);
    }
    __builtin_amdgcn_s_setprio(1);
#pragma unroll
    for (int mi = 0; mi < 4; ++mi)
#pragma unroll
      for (int ni = 0; ni < NF; ++ni)
        acc[mi][ni] = __builtin_amdgcn_mfma_f32_16x16x32_bf16(a0[mi], b0[ni], acc[mi][ni], 0, 0, 0);
    __builtin_amdgcn_s_setprio(0);
    if (ki + 2 < nk) {  // prefetch step ki+2
      const ushort* ap2 = ap + (ki + 2) * 32;
      const ushort* bp2 = bp + (ki + 2) * 32;
#pragma unroll
      for (int i = 0; i < 4; ++i) a0[i] = *(const short8v*)(ap2 + (size_t)i * 16 * K);
#pragma unroll
      for (int i = 0; i < NF; ++i) b0[i] = *(const short8v*)(bp2 + (size_t)i * 16 * K);
    }
    __builtin_amdgcn_s_setprio(1);
#pragma unroll
    for (int mi = 0; mi < 4; ++mi)
#pragma unroll
      for (int ni = 0; ni < NF; ++ni)
        acc[mi][ni] = __builtin_amdgcn_mfma_f32_16x16x32_bf16(a1[mi], b1[ni], acc[mi][ni], 0, 0, 0);
    __builtin_amdgcn_s_setprio(0);
  }
  // ---- epilogue: stage bf16 C-tile in LDS (swizzled), coalesced stores ----
#pragma unroll
  for (int mi = 0; mi < 4; ++mi)
#pragma unroll
    for (int ni = 0; ni < NF; ++ni) {
      int cl = wc + ni * 16 + lr;
#pragma unroll
      for (int i = 0; i < 4; ++i) {
        int rl = wr + mi * 16 + lg * 4 + i;
        float v = acc[mi][ni][i];
        if (RELU) v = fmaxf(v, 0.f);
        cst[rl * TN + (cl ^ (((rl >> 2) & 3) << 4))] = f2bf(v);
      }
    }
  __syncthreads();
  {
    int row = t >> 1, half = t & 1;
    int swr = ((row >> 2) & 3) << 4;
    ushort* crow = Cout + (size_t)(m0 + row) * N + n0 + half * (TN / 2);
#pragma unroll
    for (int c8 = 0; c8 < TN / 16; ++c8) {
      int c = half * (TN / 2) + c8 * 8;
      ushort8v vv = *(const ushort8v*)(&cst[row * TN + (c ^ swr)]);
      *(ushort8v*)(crow + c8 * 8) = vv;
    }
  }
}

// ---------------- flash attention: Q-tile 128, KV-tile 64, no-max softmax ----------------
__global__ __launch_bounds__(256) void k_flash(const ushort* __restrict__ qkv,
                                               ushort* __restrict__ ao) {
  __shared__ ushort Ks[64][64];
  __shared__ ushort Vt[64][64];
  __shared__ ushort Ps[4][32][64];
  const int LD = 2304;
  int qt = blockIdx.x;
  int bh = blockIdx.y;
  int h = bh % HH, b = bh / HH;
  int t = threadIdx.x, w = t >> 6, l = t & 63;
  int lr = l & 15, lg = l >> 4;
  int sw = (l & 7) << 3;
  int q0 = qt * 128;
  const ushort* qbase = qkv + (size_t)(b * SS) * LD + h * 64;
  const ushort* kbase = qbase + 768;
  const ushort* vbase = qbase + 1536;
  short8v qf[2][2];
#pragma unroll
  for (int qg = 0; qg < 2; ++qg) {
    const ushort* qrow = qbase + (size_t)(q0 + w * 32 + qg * 16 + lr) * LD + lg * 8;
    qf[qg][0] = *(const short8v*)(qrow);
    qf[qg][1] = *(const short8v*)(qrow + 32);
  }
  const float CEXP = 0.125f * 1.44269504f;
  float l_run[2] = {0.f, 0.f};
  f32x4 o_acc[2][4] = {};
  int krow_ = w * 16 + (l >> 3);
  int kcol_ = ((l & 7) * 8) ^ ((krow_ & 7) << 3);
  const ushort* kg = kbase + (size_t)krow_ * LD + kcol_;
  ushort* kl = &Ks[w * 16][0];
  int d_ = t & 7;
  int dk0 = d_ * 8;
  int kv2 = (t >> 3) * 2;
  for (int kt = 0; kt < 16; ++kt) {
    int kv0 = kt * 64;
    const ushort* vr0 = vbase + (size_t)(kv0 + kv2) * LD + dk0;
    ushort8v v0 = *(const ushort8v*)(vr0);
    ushort8v v1 = *(const ushort8v*)(vr0 + LD);
    __syncthreads();
    gload16(kg + (size_t)kv0 * LD, kl);
    gload16(kg + (size_t)(kv0 + 8) * LD, kl + 512);
#pragma unroll
    for (int i = 0; i < 8; ++i) {
      unsigned int pack = (unsigned int)v0[i] | ((unsigned int)v1[i] << 16);
      *(unsigned int*)(&Vt[dk0 + i][kv2 ^ (((i ^ d_) & 7) << 3)]) = pack;
    }
    __syncthreads();
    short8v kf[4][2];
#pragma unroll
    for (int mi = 0; mi < 4; ++mi) {
      int kvr = mi * 16 + lr;
      kf[mi][0] = *(const short8v*)(&Ks[kvr][(lg * 8) ^ sw]);
      kf[mi][1] = *(const short8v*)(&Ks[kvr][(32 + lg * 8) ^ sw]);
    }
    f32x4 s[2][4] = {};
    __builtin_amdgcn_s_setprio(1);
#pragma unroll
    for (int mi = 0; mi < 4; ++mi)
#pragma unroll
      for (int qg = 0; qg < 2; ++qg) {
        s[qg][mi] = __builtin_amdgcn_mfma_f32_16x16x32_bf16(kf[mi][0], qf[qg][0], s[qg][mi], 0, 0, 0);
        s[qg][mi] = __builtin_amdgcn_mfma_f32_16x16x32_bf16(kf[mi][1], qf[qg][1], s[qg][mi], 0, 0, 0);
      }
    __builtin_amdgcn_s_setprio(0);
#pragma unroll
    for (int qg = 0; qg < 2; ++qg) {
      float psum = 0.f;
#pragma unroll
      for (int mi = 0; mi < 4; ++mi) {
        float p0 = exp2f(s[qg][mi][0] * CEXP);
        float p1 = exp2f(s[qg][mi][1] * CEXP);
        float p2 = exp2f(s[qg][mi][2] * CEXP);
        float p3 = exp2f(s[qg][mi][3] * CEXP);
        psum += (p0 + p1) + (p2 + p3);
        uint2v pp;
        pp.x = pack_bf2(p0, p1);
        pp.y = pack_bf2(p2, p3);
        *(uint2v*)(&Ps[w][qg * 16 + lr][(mi * 16 + lg * 4) ^ ((lr & 7) << 3)]) = pp;
      }
      psum += __shfl_xor(psum, 16);
      psum += __shfl_xor(psum, 32);
      l_run[qg] += psum;
    }
#pragma unroll
    for (int ks = 0; ks < 2; ++ks) {
      short8v pf[2];
      pf[0] = *(const short8v*)(&Ps[w][lr][(ks * 32 + lg * 8) ^ sw]);
      pf[1] = *(const short8v*)(&Ps[w][16 + lr][(ks * 32 + lg * 8) ^ sw]);
      short8v vf[4];
#pragma unroll
      for (int mi = 0; mi < 4; ++mi) {
        int swz = ((lr & 7) ^ (mi * 2 + (lr >> 3))) & 7;
        vf[mi] = *(const short8v*)(&Vt[mi * 16 + lr][(ks * 32 + lg * 8) ^ (swz << 3)]);
      }
      __builtin_amdgcn_s_setprio(1);
#pragma unroll
      for (int mi = 0; mi < 4; ++mi)
#pragma unroll
        for (int qg = 0; qg < 2; ++qg)
          o_acc[qg][mi] = __builtin_amdgcn_mfma_f32_16x16x32_bf16(vf[mi], pf[qg], o_acc[qg][mi], 0, 0, 0);
      __builtin_amdgcn_s_setprio(0);
    }
  }
#pragma unroll
  for (int qg = 0; qg < 2; ++qg) {
    float invl = 1.f / l_run[qg];
    ushort* orow = ao + (size_t)(b * SS + q0 + w * 32 + qg * 16 + lr) * DD + h * 64;
#pragma unroll
    for (int mi = 0; mi < 4; ++mi) {
      ushort4v o;
#pragma unroll
      for (int i = 0; i < 4; ++i) o[i] = f2bf(o_acc[qg][mi][i] * invl);
      *(ushort4v*)(orow + mi * 16 + lg * 4) = o;
    }
  }
}

// ---------------- residual add + layernorm ----------------
__global__ __launch_bounds__(256) void k_addln(float* __restrict__ x,
                                               ushort* __restrict__ xb,
                                               const ushort* __restrict__ y,
                                               const float* __restrict__ sc,
                                               const float* __restrict__ bi) {
  __shared__ float red[4];
  int row = blockIdx.x, t = threadIdx.x;
  float* xr = x + (size_t)row * DD;
  ushort* xbr = xb + (size_t)row * DD;
  const ushort* yr = y + (size_t)row * DD;
  float vals[3];
  float s = 0.f;
#pragma unroll
  for (int i = 0; i < 3; ++i) {
    float vv = xr[t + 256 * i] + bf2f(yr[t + 256 * i]);
    vals[i] = vv;
    s += vv;
  }
  float mu = block_sum(s, red) * (1.f / 768.f);
  float vs = 0.f;
#pragma unroll
  for (int i = 0; i < 3; ++i) {
    float c = vals[i] - mu;
    vs += c * c;
  }
  float rstd = rsqrtf(block_sum(vs, red) * (1.f / 768.f) + 1e-5f);
#pragma unroll
  for (int i = 0; i < 3; ++i) {
    int d = t + 256 * i;
    float o = (vals[i] - mu) * rstd * sc[d] + bi[d];
    xr[d] = o;
    xbr[d] = f2bf(o);
  }
}

// ---------------- mean pool + classifier ----------------
__global__ __launch_bounds__(256) void k_pool(const float* __restrict__ x,
                                              float* __restrict__ pooled) {
  int b = blockIdx.x, chunk = blockIdx.y, t = threadIdx.x;
  float a0 = 0, a1 = 0, a2 = 0;
  for (int s2 = chunk * 128; s2 < chunk * 128 + 128; ++s2) {
    const float* xr = x + (size_t)(b * SS + s2) * DD;
    a0 += xr[t]; a1 += xr[t + 256]; a2 += xr[t + 512];
  }
  atomicAdd(&pooled[b * DD + t], a0 * (1.f / 1024.f));
  atomicAdd(&pooled[b * DD + t + 256], a1 * (1.f / 1024.f));
  atomicAdd(&pooled[b * DD + t + 512], a2 * (1.f / 1024.f));
}

__global__ __launch_bounds__(64) void k_cls(const float* __restrict__ pooled,
                                            const float* __restrict__ Wc,
                                            const float* __restrict__ bc,
                                            float* __restrict__ out) {
  int idx = blockIdx.x;
  int b = idx / CC, c = idx % CC;
  int t = threadIdx.x;
  float acc = 0.f;
  for (int d0 = t; d0 < DD; d0 += 64) acc = fmaf(pooled[b * DD + d0], Wc[d0 * CC + c], acc);
  acc = wave_sum(acc);
  if (t == 0) out[b * CC + c] = acc + bc[c];
}

extern "C" void kernel_launch(void* const* d_in, const int* in_sizes, int n_in,
                              void* d_out, int out_size, void* d_ws, size_t ws_size,
                              hipStream_t stream) {
  (void)in_sizes; (void)n_in; (void)out_size; (void)ws_size;
  const int* tokens = (const int*)d_in[0];
  const float* emb = (const float*)d_in[1];
  const float* Wq = (const float*)d_in[2];
  const float* Wk = (const float*)d_in[3];
  const float* Wv = (const float*)d_in[4];
  const float* Wo = (const float*)d_in[5];
  const float* W1 = (const float*)d_in[6];
  const float* W2 = (const float*)d_in[7];
  const float* l1s = (const float*)d_in[8];
  const float* l1b = (const float*)d_in[9];
  const float* l2s = (const float*)d_in[10];
  const float* l2b = (const float*)d_in[11];
  const float* Wc = (const float*)d_in[12];
  const float* bc = (const float*)d_in[13];
  float* out = (float*)d_out;

  char* p = (char*)d_ws;
  float* x = (float*)p;                 p += (size_t)BS_ * DD * 4;
  ushort* xb = (ushort*)p;              p += (size_t)BS_ * DD * 2;
  ushort* qkvb = (ushort*)p;            // [8192][2304]
  ushort* hb = (ushort*)p;              // [8192][3072] overlay
  ushort* ao = (ushort*)(p + (size_t)BS_ * 2304 * 2);
  p += (size_t)BS_ * FF * 2;
  ushort* yb = (ushort*)p;              p += (size_t)BS_ * DD * 2;
  ushort* wt = (ushort*)p;              p += (size_t)(2304 * 768 + 768 * 768 + 3072 * 768 + 768 * 3072) * 2;
  float* pooled = (float*)p;

  ushort* wqkv_t = wt;                        // [2304][768]
  ushort* wo_t = wqkv_t + 2304 * 768;         // [768][768]
  ushort* w1_t = wo_t + 768 * 768;            // [3072][768]
  ushort* w2_t = w1_t + 3072 * 768;           // [768][3072]

  k_embed<<<BS_, 256, 0, stream>>>(tokens, emb, x, xb);

  for (int l = 0; l < LL; ++l) {
    k_transpose_all<<<6912, 256, 0, stream>>>(
        Wq + (size_t)l * DD * DD, Wk + (size_t)l * DD * DD,
        Wv + (size_t)l * DD * DD, Wo + (size_t)l * DD * DD,
        W1 + (size_t)l * DD * FF, W2 + (size_t)l * FF * DD,
        wqkv_t, wo_t, w1_t, w2_t);

    k_gemm_flat<0, 128><<<dim3(2304 / 128, BS_ / 128), 256, 0, stream>>>(xb, wqkv_t, qkvb, BS_, 2304, DD);
    k_flash<<<dim3(SS / 128, BB * HH), 256, 0, stream>>>(qkvb, ao);
    k_gemm_flat<0, 64><<<dim3(DD / 64, BS_ / 128), 256, 0, stream>>>(ao, wo_t, yb, BS_, DD, DD);
    k_addln<<<BS_, 256, 0, stream>>>(x, xb, yb, l1s + l * DD, l1b + l * DD);
    k_gemm_flat<1, 128><<<dim3(FF / 128, BS_ / 128), 256, 0, stream>>>(xb, w1_t, hb, BS_, FF, DD);
    k_gemm_flat<0, 64><<<dim3(DD / 64, BS_ / 128), 256, 0, stream>>>(hb, w2_t, yb, BS_, DD, FF);
    k_addln<<<BS_, 256, 0, stream>>>(x, xb, yb, l2s + l * DD, l2b + l * DD);
  }

  hipMemsetAsync(pooled, 0, (size_t)BB * DD * sizeof(float), stream);
  k_pool<<<dim3(BB, 8), 256, 0, stream>>>(x, pooled);
  k_cls<<<BB * CC, 64, 0, stream>>>(pooled, Wc, bc, out);
}

// Round 6
// 1718.546 us; speedup vs baseline: 2.0981x; 2.0981x over previous
//
#include <hip/hip_runtime.h>
#include <hip/hip_bf16.h>
#include <math.h>

#define BB 8
#define SS 1024
#define DD 768
#define HH 12
#define LL 6
#define FF 3072
#define CC 10
#define BS_ (BB * SS)   // 8192 rows

typedef __attribute__((ext_vector_type(8))) short short8v;       // bf16x8 MFMA frag
typedef __attribute__((ext_vector_type(4))) float f32x4;         // MFMA acc
typedef __attribute__((ext_vector_type(8))) unsigned short ushort8v;
typedef __attribute__((ext_vector_type(4))) unsigned short ushort4v;
typedef __attribute__((ext_vector_type(2))) unsigned int uint2v;

__device__ inline unsigned short f2bf(float f) {
  unsigned int u = __builtin_bit_cast(unsigned int, f);
  u += 0x7fffu + ((u >> 16) & 1u);
  return (unsigned short)(u >> 16);
}
__device__ inline float bf2f(unsigned short u) {
  return __builtin_bit_cast(float, (unsigned int)u << 16);
}
__device__ inline unsigned int pack_bf2(float lo, float hi) {
  unsigned int a = __builtin_bit_cast(unsigned int, lo);
  unsigned int b = __builtin_bit_cast(unsigned int, hi);
  a += 0x7fffu + ((a >> 16) & 1u);
  b += 0x7fffu + ((b >> 16) & 1u);
  return __builtin_amdgcn_perm(b, a, 0x07060302u);
}
__device__ inline void gload16(const void* g, void* l) {
  __builtin_amdgcn_global_load_lds((const __attribute__((address_space(1))) void*)g,
                                   (__attribute__((address_space(3))) void*)l, 16, 0, 0);
}

// ---------------- reduction helpers ----------------
__device__ inline float wave_sum(float v) {
#pragma unroll
  for (int off = 32; off > 0; off >>= 1) v += __shfl_down(v, off);
  return v;
}
__device__ inline float block_sum(float v, float* red) {
  int t = threadIdx.x;
  v = wave_sum(v);
  __syncthreads();
  if ((t & 63) == 0) red[t >> 6] = v;
  __syncthreads();
  return red[0] + red[1] + red[2] + red[3];
}

// ---------------- embedding + sinusoidal PE ----------------
__global__ __launch_bounds__(256) void k_embed(const int* __restrict__ tokens,
                                               const float* __restrict__ emb,
                                               float* __restrict__ x,
                                               ushort* __restrict__ xb) {
  int row = blockIdx.x;
  int s = row & (SS - 1);
  int tok = tokens[row];
  const float* e = emb + (size_t)tok * DD;
  float* xr = x + (size_t)row * DD;
  ushort* xbr = xb + (size_t)row * DD;
  for (int d = threadIdx.x; d < DD; d += 256) {
    float freq = expf((float)(d & ~1) * -0.0119926306f);
    float ang = (float)s * freq;
    float pe = (d & 1) ? cosf(ang) : sinf(ang);
    float v = e[d] + pe;
    xr[d] = v;
    xbr[d] = f2bf(v);
  }
}

// ---------------- fused per-layer weight transpose ----------------
__global__ __launch_bounds__(256) void k_transpose_all(
    const float* __restrict__ wq, const float* __restrict__ wk,
    const float* __restrict__ wv, const float* __restrict__ wo,
    const float* __restrict__ w1, const float* __restrict__ w2,
    ushort* __restrict__ wqkv_t, ushort* __restrict__ wo_t,
    ushort* __restrict__ w1_t, ushort* __restrict__ w2_t) {
  __shared__ float tile[32][33];
  int bid = blockIdx.x;
  const float* W; ushort* Wt; int K, N, lb;
  if (bid < 1728) {
    int m = bid / 576; lb = bid - m * 576;
    W = (m == 0) ? wq : (m == 1) ? wk : wv;
    Wt = wqkv_t + m * 768 * 768; K = 768; N = 768;
  } else if (bid < 2304) {
    W = wo; Wt = wo_t; K = 768; N = 768; lb = bid - 1728;
  } else if (bid < 4608) {
    W = w1; Wt = w1_t; K = 768; N = 3072; lb = bid - 2304;
  } else {
    W = w2; Wt = w2_t; K = 3072; N = 768; lb = bid - 4608;
  }
  int nbk = K >> 5;
  int k0 = (lb % nbk) * 32, n0 = (lb / nbk) * 32;
  int t = threadIdx.x;
  int r = t >> 3, c4 = (t & 7) * 4;
  float4 v = *(const float4*)(W + (size_t)(k0 + r) * N + n0 + c4);
  tile[r][c4 + 0] = v.x; tile[r][c4 + 1] = v.y;
  tile[r][c4 + 2] = v.z; tile[r][c4 + 3] = v.w;
  __syncthreads();
  ushort4v o;
#pragma unroll
  for (int i = 0; i < 4; ++i) o[i] = f2bf(tile[c4 + i][r]);
  *(ushort4v*)(Wt + (size_t)(n0 + r) * K + k0 + c4) = o;
}

// ---------------- bf16 MFMA GEMM, double-buffered LDS pipeline ----------------
// C[M,N](bf16) = A[M,K] @ Bt[N,K]^T. 128xTN tile, BK=64, 4 waves.
// global_load_lds staging issued one K-step ahead (loads fly during compute);
// ONE barrier per K-step. Chunked XCD swizzle on the tile index.
template <int RELU, int TN>
__global__ __launch_bounds__(256) void k_gemm_db(const ushort* __restrict__ A,
                                                 const ushort* __restrict__ Bt,
                                                 ushort* __restrict__ Cout,
                                                 int M, int N, int K) {
  constexpr int NF = TN / 32;            // B frags per wave
  __shared__ ushort smem[2][(128 + TN) * 64];
  // chunked XCD swizzle (nwg is a multiple of 8 for all our grids)
  int bidl = blockIdx.y * gridDim.x + blockIdx.x;
  int nwg = gridDim.x * gridDim.y;
  int cpx = nwg >> 3;
  int tid = (bidl & 7) * cpx + (bidl >> 3);
  int n0 = (tid % gridDim.x) * TN, m0 = (tid / gridDim.x) * 128;
  int t = threadIdx.x, w = t >> 6, l = t & 63;
  int wr = (w >> 1) * 64, wc = (w & 1) * (TN / 2);
  int lr = l & 15, lg = l >> 4;
  f32x4 acc[4][NF] = {};
  // staging geometry: per instr, 256 thr x 16B = 32 rows of 64 cols
  const ushort* ag = A + (size_t)(m0 + w * 8 + (l >> 3)) * K + (l & 7) * 8;
  const ushort* bg = Bt + (size_t)(n0 + w * 8 + (l >> 3)) * K + (l & 7) * 8;
  int nk = K >> 6;
  // prologue: stage tile 0 into buf 0
  {
    ushort* al = &smem[0][(w * 8) * 64];
    ushort* bl = &smem[0][128 * 64 + (w * 8) * 64];
#pragma unroll
    for (int ii = 0; ii < 4; ++ii) gload16(ag + (size_t)ii * 32 * K, al + ii * 2048);
#pragma unroll
    for (int ii = 0; ii < TN / 32; ++ii) gload16(bg + (size_t)ii * 32 * K, bl + ii * 2048);
  }
  for (int k = 0; k < nk; ++k) {
    __syncthreads();   // implicit vmcnt(0): tile k staged; prev-tile reads done
    if (k + 1 < nk) {  // stage tile k+1 into the other buffer (flies during compute)
      int kb = (k + 1) & 1;
      int kc0 = (k + 1) * 64;
      ushort* al = &smem[kb][(w * 8) * 64];
      ushort* bl = &smem[kb][128 * 64 + (w * 8) * 64];
#pragma unroll
      for (int ii = 0; ii < 4; ++ii) gload16(ag + (size_t)ii * 32 * K + kc0, al + ii * 2048);
#pragma unroll
      for (int ii = 0; ii < TN / 32; ++ii) gload16(bg + (size_t)ii * 32 * K + kc0, bl + ii * 2048);
    }
    const ushort* As = &smem[k & 1][0];
    const ushort* Bs = &smem[k & 1][128 * 64];
#pragma unroll
    for (int ks = 0; ks < 2; ++ks) {
      int kc = ks * 32 + lg * 8;
      short8v af[4], bfr[NF];
#pragma unroll
      for (int mi = 0; mi < 4; ++mi) af[mi] = *(const short8v*)(As + (wr + mi * 16 + lr) * 64 + kc);
#pragma unroll
      for (int ni = 0; ni < NF; ++ni) bfr[ni] = *(const short8v*)(Bs + (wc + ni * 16 + lr) * 64 + kc);
      __builtin_amdgcn_s_setprio(1);
#pragma unroll
      for (int mi = 0; mi < 4; ++mi)
#pragma unroll
        for (int ni = 0; ni < NF; ++ni)
          acc[mi][ni] = __builtin_amdgcn_mfma_f32_16x16x32_bf16(af[mi], bfr[ni], acc[mi][ni], 0, 0, 0);
      __builtin_amdgcn_s_setprio(0);
    }
  }
  // ---- epilogue: stage bf16 C-tile in LDS (swizzled), coalesced stores ----
  __syncthreads();
  ushort* cst = &smem[0][0];
#pragma unroll
  for (int mi = 0; mi < 4; ++mi)
#pragma unroll
    for (int ni = 0; ni < NF; ++ni) {
      int cl = wc + ni * 16 + lr;
#pragma unroll
      for (int i = 0; i < 4; ++i) {
        int rl = wr + mi * 16 + lg * 4 + i;
        float v = acc[mi][ni][i];
        if (RELU) v = fmaxf(v, 0.f);
        cst[rl * TN + (cl ^ (((rl >> 2) & 3) << 4))] = f2bf(v);
      }
    }
  __syncthreads();
  {
    int row = t >> 1, half = t & 1;
    int swr = ((row >> 2) & 3) << 4;
    ushort* crow = Cout + (size_t)(m0 + row) * N + n0 + half * (TN / 2);
#pragma unroll
    for (int c8 = 0; c8 < TN / 16; ++c8) {
      int c = half * (TN / 2) + c8 * 8;
      ushort8v vv = *(const ushort8v*)(&cst[row * TN + (c ^ swr)]);
      *(ushort8v*)(crow + c8 * 8) = vv;
    }
  }
}

// ---------------- flash attention: Q-tile 128, KV-tile 64, no-max softmax ----------------
__global__ __launch_bounds__(256) void k_flash(const ushort* __restrict__ qkv,
                                               ushort* __restrict__ ao) {
  __shared__ ushort Ks[64][64];
  __shared__ ushort Vt[64][64];
  __shared__ ushort Ps[4][32][64];
  const int LD = 2304;
  // chunked XCD swizzle: group all q-tiles of one (b,h) on one XCD (KV reuse)
  int bidl = blockIdx.y * gridDim.x + blockIdx.x;   // grid 8 x 96 = 768
  int tid = (bidl & 7) * 96 + (bidl >> 3);
  int qt = tid & 7;
  int bh = tid >> 3;
  int h = bh % HH, b = bh / HH;
  int t = threadIdx.x, w = t >> 6, l = t & 63;
  int lr = l & 15, lg = l >> 4;
  int sw = (l & 7) << 3;
  int q0 = qt * 128;
  const ushort* qbase = qkv + (size_t)(b * SS) * LD + h * 64;
  const ushort* kbase = qbase + 768;
  const ushort* vbase = qbase + 1536;
  short8v qf[2][2];
#pragma unroll
  for (int qg = 0; qg < 2; ++qg) {
    const ushort* qrow = qbase + (size_t)(q0 + w * 32 + qg * 16 + lr) * LD + lg * 8;
    qf[qg][0] = *(const short8v*)(qrow);
    qf[qg][1] = *(const short8v*)(qrow + 32);
  }
  const float CEXP = 0.125f * 1.44269504f;
  float l_run[2] = {0.f, 0.f};
  f32x4 o_acc[2][4] = {};
  int krow_ = w * 16 + (l >> 3);
  int kcol_ = ((l & 7) * 8) ^ ((krow_ & 7) << 3);
  const ushort* kg = kbase + (size_t)krow_ * LD + kcol_;
  ushort* kl = &Ks[w * 16][0];
  int d_ = t & 7;
  int dk0 = d_ * 8;
  int kv2 = (t >> 3) * 2;
  for (int kt = 0; kt < 16; ++kt) {
    int kv0 = kt * 64;
    const ushort* vr0 = vbase + (size_t)(kv0 + kv2) * LD + dk0;
    ushort8v v0 = *(const ushort8v*)(vr0);
    ushort8v v1 = *(const ushort8v*)(vr0 + LD);
    __syncthreads();
    gload16(kg + (size_t)kv0 * LD, kl);
    gload16(kg + (size_t)(kv0 + 8) * LD, kl + 512);
#pragma unroll
    for (int i = 0; i < 8; ++i) {
      unsigned int pack = (unsigned int)v0[i] | ((unsigned int)v1[i] << 16);
      *(unsigned int*)(&Vt[dk0 + i][kv2 ^ (((i ^ d_) & 7) << 3)]) = pack;
    }
    __syncthreads();
    short8v kf[4][2];
#pragma unroll
    for (int mi = 0; mi < 4; ++mi) {
      int kvr = mi * 16 + lr;
      kf[mi][0] = *(const short8v*)(&Ks[kvr][(lg * 8) ^ sw]);
      kf[mi][1] = *(const short8v*)(&Ks[kvr][(32 + lg * 8) ^ sw]);
    }
    f32x4 s[2][4] = {};
    __builtin_amdgcn_s_setprio(1);
#pragma unroll
    for (int mi = 0; mi < 4; ++mi)
#pragma unroll
      for (int qg = 0; qg < 2; ++qg) {
        s[qg][mi] = __builtin_amdgcn_mfma_f32_16x16x32_bf16(kf[mi][0], qf[qg][0], s[qg][mi], 0, 0, 0);
        s[qg][mi] = __builtin_amdgcn_mfma_f32_16x16x32_bf16(kf[mi][1], qf[qg][1], s[qg][mi], 0, 0, 0);
      }
    __builtin_amdgcn_s_setprio(0);
#pragma unroll
    for (int qg = 0; qg < 2; ++qg) {
      float psum = 0.f;
#pragma unroll
      for (int mi = 0; mi < 4; ++mi) {
        float p0 = exp2f(s[qg][mi][0] * CEXP);
        float p1 = exp2f(s[qg][mi][1] * CEXP);
        float p2 = exp2f(s[qg][mi][2] * CEXP);
        float p3 = exp2f(s[qg][mi][3] * CEXP);
        psum += (p0 + p1) + (p2 + p3);
        uint2v pp;
        pp.x = pack_bf2(p0, p1);
        pp.y = pack_bf2(p2, p3);
        *(uint2v*)(&Ps[w][qg * 16 + lr][(mi * 16 + lg * 4) ^ ((lr & 7) << 3)]) = pp;
      }
      psum += __shfl_xor(psum, 16);
      psum += __shfl_xor(psum, 32);
      l_run[qg] += psum;
    }
#pragma unroll
    for (int ks = 0; ks < 2; ++ks) {
      short8v pf[2];
      pf[0] = *(const short8v*)(&Ps[w][lr][(ks * 32 + lg * 8) ^ sw]);
      pf[1] = *(const short8v*)(&Ps[w][16 + lr][(ks * 32 + lg * 8) ^ sw]);
      short8v vf[4];
#pragma unroll
      for (int mi = 0; mi < 4; ++mi) {
        int swz = ((lr & 7) ^ (mi * 2 + (lr >> 3))) & 7;
        vf[mi] = *(const short8v*)(&Vt[mi * 16 + lr][(ks * 32 + lg * 8) ^ (swz << 3)]);
      }
      __builtin_amdgcn_s_setprio(1);
#pragma unroll
      for (int mi = 0; mi < 4; ++mi)
#pragma unroll
        for (int qg = 0; qg < 2; ++qg)
          o_acc[qg][mi] = __builtin_amdgcn_mfma_f32_16x16x32_bf16(vf[mi], pf[qg], o_acc[qg][mi], 0, 0, 0);
      __builtin_amdgcn_s_setprio(0);
    }
  }
#pragma unroll
  for (int qg = 0; qg < 2; ++qg) {
    float invl = 1.f / l_run[qg];
    ushort* orow = ao + (size_t)(b * SS + q0 + w * 32 + qg * 16 + lr) * DD + h * 64;
#pragma unroll
    for (int mi = 0; mi < 4; ++mi) {
      ushort4v o;
#pragma unroll
      for (int i = 0; i < 4; ++i) o[i] = f2bf(o_acc[qg][mi][i] * invl);
      *(ushort4v*)(orow + mi * 16 + lg * 4) = o;
    }
  }
}

// ---------------- residual add + layernorm ----------------
__global__ __launch_bounds__(256) void k_addln(float* __restrict__ x,
                                               ushort* __restrict__ xb,
                                               const ushort* __restrict__ y,
                                               const float* __restrict__ sc,
                                               const float* __restrict__ bi) {
  __shared__ float red[4];
  int row = blockIdx.x, t = threadIdx.x;
  float* xr = x + (size_t)row * DD;
  ushort* xbr = xb + (size_t)row * DD;
  const ushort* yr = y + (size_t)row * DD;
  float vals[3];
  float s = 0.f;
#pragma unroll
  for (int i = 0; i < 3; ++i) {
    float vv = xr[t + 256 * i] + bf2f(yr[t + 256 * i]);
    vals[i] = vv;
    s += vv;
  }
  float mu = block_sum(s, red) * (1.f / 768.f);
  float vs = 0.f;
#pragma unroll
  for (int i = 0; i < 3; ++i) {
    float c = vals[i] - mu;
    vs += c * c;
  }
  float rstd = rsqrtf(block_sum(vs, red) * (1.f / 768.f) + 1e-5f);
#pragma unroll
  for (int i = 0; i < 3; ++i) {
    int d = t + 256 * i;
    float o = (vals[i] - mu) * rstd * sc[d] + bi[d];
    xr[d] = o;
    xbr[d] = f2bf(o);
  }
}

// ---------------- mean pool + classifier ----------------
__global__ __launch_bounds__(256) void k_pool(const float* __restrict__ x,
                                              float* __restrict__ pooled) {
  int b = blockIdx.x, chunk = blockIdx.y, t = threadIdx.x;
  float a0 = 0, a1 = 0, a2 = 0;
  for (int s2 = chunk * 128; s2 < chunk * 128 + 128; ++s2) {
    const float* xr = x + (size_t)(b * SS + s2) * DD;
    a0 += xr[t]; a1 += xr[t + 256]; a2 += xr[t + 512];
  }
  atomicAdd(&pooled[b * DD + t], a0 * (1.f / 1024.f));
  atomicAdd(&pooled[b * DD + t + 256], a1 * (1.f / 1024.f));
  atomicAdd(&pooled[b * DD + t + 512], a2 * (1.f / 1024.f));
}

__global__ __launch_bounds__(64) void k_cls(const float* __restrict__ pooled,
                                            const float* __restrict__ Wc,
                                            const float* __restrict__ bc,
                                            float* __restrict__ out) {
  int idx = blockIdx.x;
  int b = idx / CC, c = idx % CC;
  int t = threadIdx.x;
  float acc = 0.f;
  for (int d0 = t; d0 < DD; d0 += 64) acc = fmaf(pooled[b * DD + d0], Wc[d0 * CC + c], acc);
  acc = wave_sum(acc);
  if (t == 0) out[b * CC + c] = acc + bc[c];
}

extern "C" void kernel_launch(void* const* d_in, const int* in_sizes, int n_in,
                              void* d_out, int out_size, void* d_ws, size_t ws_size,
                              hipStream_t stream) {
  (void)in_sizes; (void)n_in; (void)out_size; (void)ws_size;
  const int* tokens = (const int*)d_in[0];
  const float* emb = (const float*)d_in[1];
  const float* Wq = (const float*)d_in[2];
  const float* Wk = (const float*)d_in[3];
  const float* Wv = (const float*)d_in[4];
  const float* Wo = (const float*)d_in[5];
  const float* W1 = (const float*)d_in[6];
  const float* W2 = (const float*)d_in[7];
  const float* l1s = (const float*)d_in[8];
  const float* l1b = (const float*)d_in[9];
  const float* l2s = (const float*)d_in[10];
  const float* l2b = (const float*)d_in[11];
  const float* Wc = (const float*)d_in[12];
  const float* bc = (const float*)d_in[13];
  float* out = (float*)d_out;

  char* p = (char*)d_ws;
  float* x = (float*)p;                 p += (size_t)BS_ * DD * 4;
  ushort* xb = (ushort*)p;              p += (size_t)BS_ * DD * 2;
  ushort* qkvb = (ushort*)p;            // [8192][2304]
  ushort* hb = (ushort*)p;              // [8192][3072] overlay
  ushort* ao = (ushort*)(p + (size_t)BS_ * 2304 * 2);
  p += (size_t)BS_ * FF * 2;
  ushort* yb = (ushort*)p;              p += (size_t)BS_ * DD * 2;
  ushort* wt = (ushort*)p;              p += (size_t)(2304 * 768 + 768 * 768 + 3072 * 768 + 768 * 3072) * 2;
  float* pooled = (float*)p;

  ushort* wqkv_t = wt;                        // [2304][768]
  ushort* wo_t = wqkv_t + 2304 * 768;         // [768][768]
  ushort* w1_t = wo_t + 768 * 768;            // [3072][768]
  ushort* w2_t = w1_t + 3072 * 768;           // [768][3072]

  k_embed<<<BS_, 256, 0, stream>>>(tokens, emb, x, xb);

  for (int l = 0; l < LL; ++l) {
    k_transpose_all<<<6912, 256, 0, stream>>>(
        Wq + (size_t)l * DD * DD, Wk + (size_t)l * DD * DD,
        Wv + (size_t)l * DD * DD, Wo + (size_t)l * DD * DD,
        W1 + (size_t)l * DD * FF, W2 + (size_t)l * FF * DD,
        wqkv_t, wo_t, w1_t, w2_t);

    k_gemm_db<0, 128><<<dim3(2304 / 128, BS_ / 128), 256, 0, stream>>>(xb, wqkv_t, qkvb, BS_, 2304, DD);
    k_flash<<<dim3(SS / 128, BB * HH), 256, 0, stream>>>(qkvb, ao);
    k_gemm_db<0, 64><<<dim3(DD / 64, BS_ / 128), 256, 0, stream>>>(ao, wo_t, yb, BS_, DD, DD);
    k_addln<<<BS_, 256, 0, stream>>>(x, xb, yb, l1s + l * DD, l1b + l * DD);
    k_gemm_db<1, 128><<<dim3(FF / 128, BS_ / 128), 256, 0, stream>>>(xb, w1_t, hb, BS_, FF, DD);
    k_gemm_db<0, 64><<<dim3(DD / 64, BS_ / 128), 256, 0, stream>>>(hb, w2_t, yb, BS_, DD, FF);
    k_addln<<<BS_, 256, 0, stream>>>(x, xb, yb, l2s + l * DD, l2b + l * DD);
  }

  hipMemsetAsync(pooled, 0, (size_t)BB * DD * sizeof(float), stream);
  k_pool<<<dim3(BB, 8), 256, 0, stream>>>(x, pooled);
  k_cls<<<BB * CC, 64, 0, stream>>>(pooled, Wc, bc, out);
}

// Round 7
// 1486.783 us; speedup vs baseline: 2.4251x; 1.1559x over previous
//
#include <hip/hip_runtime.h>
#include <hip/hip_bf16.h>
#include <math.h>

#define BB 8
#define SS 1024
#define DD 768
#define HH 12
#define LL 6
#define FF 3072
#define CC 10
#define BS_ (BB * SS)   // 8192 rows

typedef __attribute__((ext_vector_type(8))) short short8v;       // bf16x8 MFMA frag
typedef __attribute__((ext_vector_type(4))) float f32x4;         // MFMA acc
typedef __attribute__((ext_vector_type(8))) unsigned short ushort8v;
typedef __attribute__((ext_vector_type(4))) unsigned short ushort4v;
typedef __attribute__((ext_vector_type(2))) unsigned int uint2v;

__device__ inline unsigned short f2bf(float f) {
  unsigned int u = __builtin_bit_cast(unsigned int, f);
  u += 0x7fffu + ((u >> 16) & 1u);
  return (unsigned short)(u >> 16);
}
__device__ inline float bf2f(unsigned short u) {
  return __builtin_bit_cast(float, (unsigned int)u << 16);
}
__device__ inline unsigned int pack_bf2(float lo, float hi) {
  unsigned int a = __builtin_bit_cast(unsigned int, lo);
  unsigned int b = __builtin_bit_cast(unsigned int, hi);
  a += 0x7fffu + ((a >> 16) & 1u);
  b += 0x7fffu + ((b >> 16) & 1u);
  return __builtin_amdgcn_perm(b, a, 0x07060302u);
}
__device__ inline void gload16(const void* g, void* l) {
  __builtin_amdgcn_global_load_lds((const __attribute__((address_space(1))) void*)g,
                                   (__attribute__((address_space(3))) void*)l, 16, 0, 0);
}

// ---------------- reduction helpers ----------------
__device__ inline float wave_sum(float v) {
#pragma unroll
  for (int off = 32; off > 0; off >>= 1) v += __shfl_down(v, off);
  return v;
}
__device__ inline float block_sum(float v, float* red) {
  int t = threadIdx.x;
  v = wave_sum(v);
  __syncthreads();
  if ((t & 63) == 0) red[t >> 6] = v;
  __syncthreads();
  return red[0] + red[1] + red[2] + red[3];
}

// ---------------- embedding + sinusoidal PE ----------------
__global__ __launch_bounds__(256) void k_embed(const int* __restrict__ tokens,
                                               const float* __restrict__ emb,
                                               float* __restrict__ x,
                                               ushort* __restrict__ xb) {
  int row = blockIdx.x;
  int s = row & (SS - 1);
  int tok = tokens[row];
  const float* e = emb + (size_t)tok * DD;
  float* xr = x + (size_t)row * DD;
  ushort* xbr = xb + (size_t)row * DD;
  for (int d = threadIdx.x; d < DD; d += 256) {
    float freq = expf((float)(d & ~1) * -0.0119926306f);
    float ang = (float)s * freq;
    float pe = (d & 1) ? cosf(ang) : sinf(ang);
    float v = e[d] + pe;
    xr[d] = v;
    xbr[d] = f2bf(v);
  }
}

// ---------------- fused per-layer weight transpose ----------------
__global__ __launch_bounds__(256) void k_transpose_all(
    const float* __restrict__ wq, const float* __restrict__ wk,
    const float* __restrict__ wv, const float* __restrict__ wo,
    const float* __restrict__ w1, const float* __restrict__ w2,
    ushort* __restrict__ wqkv_t, ushort* __restrict__ wo_t,
    ushort* __restrict__ w1_t, ushort* __restrict__ w2_t) {
  __shared__ float tile[32][33];
  int bid = blockIdx.x;
  const float* W; ushort* Wt; int K, N, lb;
  if (bid < 1728) {
    int m = bid / 576; lb = bid - m * 576;
    W = (m == 0) ? wq : (m == 1) ? wk : wv;
    Wt = wqkv_t + m * 768 * 768; K = 768; N = 768;
  } else if (bid < 2304) {
    W = wo; Wt = wo_t; K = 768; N = 768; lb = bid - 1728;
  } else if (bid < 4608) {
    W = w1; Wt = w1_t; K = 768; N = 3072; lb = bid - 2304;
  } else {
    W = w2; Wt = w2_t; K = 3072; N = 768; lb = bid - 4608;
  }
  int nbk = K >> 5;
  int k0 = (lb % nbk) * 32, n0 = (lb / nbk) * 32;
  int t = threadIdx.x;
  int r = t >> 3, c4 = (t & 7) * 4;
  float4 v = *(const float4*)(W + (size_t)(k0 + r) * N + n0 + c4);
  tile[r][c4 + 0] = v.x; tile[r][c4 + 1] = v.y;
  tile[r][c4 + 2] = v.z; tile[r][c4 + 3] = v.w;
  __syncthreads();
  ushort4v o;
#pragma unroll
  for (int i = 0; i < 4; ++i) o[i] = f2bf(tile[c4 + i][r]);
  *(ushort4v*)(Wt + (size_t)(n0 + r) * K + k0 + c4) = o;
}

// ---------------- bf16 MFMA GEMM, double-buffered + T2 XOR-swizzled LDS ----------------
// C[M,N](bf16) = A[M,K] @ Bt[N,K]^T. 128xTN tile, BK=64, 4 waves.
// Staging: global_load_lds 16B/lane, LINEAR LDS dest; the 16B-chunk swizzle
// chunk' = chunk ^ (row&7) is applied by pre-swizzling the GLOBAL source
// (rule 21) and XORing on the fragment ds_read. One barrier per K-step.
template <int RELU, int TN>
__global__ __launch_bounds__(256) void k_gemm_db(const ushort* __restrict__ A,
                                                 const ushort* __restrict__ Bt,
                                                 ushort* __restrict__ Cout,
                                                 int M, int N, int K) {
  constexpr int NF = TN / 32;            // B frags per wave
  __shared__ ushort smem[2][(128 + TN) * 64];
  // chunked XCD swizzle (all our grids have nwg % 8 == 0)
  int bidl = blockIdx.y * gridDim.x + blockIdx.x;
  int nwg = gridDim.x * gridDim.y;
  int cpx = nwg >> 3;
  int tid = (bidl & 7) * cpx + (bidl >> 3);
  int n0 = (tid % gridDim.x) * TN, m0 = (tid / gridDim.x) * 128;
  int t = threadIdx.x, w = t >> 6, l = t & 63;
  int wr = (w >> 1) * 64, wc = (w & 1) * (TN / 2);
  int lr = l & 15, lg = l >> 4;
  f32x4 acc[4][NF] = {};
  // staging geometry: per instr, 256 thr x 16B = 32 rows x 8 chunks (linear dest).
  // source chunk pre-swizzled so LDS[row][c] = G[row][c ^ (row&7)].
  int sr8 = l >> 3;                       // row within the 8-row stripe
  int scw = ((l & 7) ^ sr8) * 8;          // inverse-swizzled source col (ushorts)
  const ushort* ag = A + (size_t)(m0 + w * 8 + sr8) * K + scw;
  const ushort* bg = Bt + (size_t)(n0 + w * 8 + sr8) * K + scw;
  int nk = K >> 6;
  // prologue: stage tile 0 into buf 0
  {
    ushort* al = &smem[0][(w * 8) * 64];
    ushort* bl = &smem[0][128 * 64 + (w * 8) * 64];
#pragma unroll
    for (int ii = 0; ii < 4; ++ii) gload16(ag + (size_t)ii * 32 * K, al + ii * 2048);
#pragma unroll
    for (int ii = 0; ii < TN / 32; ++ii) gload16(bg + (size_t)ii * 32 * K, bl + ii * 2048);
  }
  int rsw = lr & 7;                       // fragment-read swizzle (row&7)
  for (int k = 0; k < nk; ++k) {
    __syncthreads();   // implicit vmcnt(0): tile k staged; prev-tile reads done
    if (k + 1 < nk) {  // stage tile k+1 (loads fly during compute of tile k)
      int kb = (k + 1) & 1;
      int kc0 = (k + 1) * 64;
      ushort* al = &smem[kb][(w * 8) * 64];
      ushort* bl = &smem[kb][128 * 64 + (w * 8) * 64];
#pragma unroll
      for (int ii = 0; ii < 4; ++ii) gload16(ag + (size_t)ii * 32 * K + kc0, al + ii * 2048);
#pragma unroll
      for (int ii = 0; ii < TN / 32; ++ii) gload16(bg + (size_t)ii * 32 * K + kc0, bl + ii * 2048);
    }
    const ushort* As = &smem[k & 1][0];
    const ushort* Bs = &smem[k & 1][128 * 64];
#pragma unroll
    for (int ks = 0; ks < 2; ++ks) {
      short8v af[4], bfr[NF];
#pragma unroll
      for (int mi = 0; mi < 4; ++mi)
        af[mi] = *(const short8v*)(As + (wr + mi * 16 + lr) * 64 + (((ks * 4 + lg) ^ rsw) << 3));
#pragma unroll
      for (int ni = 0; ni < NF; ++ni)
        bfr[ni] = *(const short8v*)(Bs + (wc + ni * 16 + lr) * 64 + (((ks * 4 + lg) ^ rsw) << 3));
      __builtin_amdgcn_s_setprio(1);
#pragma unroll
      for (int mi = 0; mi < 4; ++mi)
#pragma unroll
        for (int ni = 0; ni < NF; ++ni)
          acc[mi][ni] = __builtin_amdgcn_mfma_f32_16x16x32_bf16(af[mi], bfr[ni], acc[mi][ni], 0, 0, 0);
      __builtin_amdgcn_s_setprio(0);
    }
  }
  // ---- epilogue: stage bf16 C-tile in LDS (swizzled), coalesced stores ----
  __syncthreads();
  ushort* cst = &smem[0][0];
#pragma unroll
  for (int mi = 0; mi < 4; ++mi)
#pragma unroll
    for (int ni = 0; ni < NF; ++ni) {
      int cl = wc + ni * 16 + lr;
#pragma unroll
      for (int i = 0; i < 4; ++i) {
        int rl = wr + mi * 16 + lg * 4 + i;
        float v = acc[mi][ni][i];
        if (RELU) v = fmaxf(v, 0.f);
        cst[rl * TN + (cl ^ (((rl >> 2) & 3) << 4))] = f2bf(v);
      }
    }
  __syncthreads();
  {
    int row = t >> 1, half = t & 1;
    int swr = ((row >> 2) & 3) << 4;
    ushort* crow = Cout + (size_t)(m0 + row) * N + n0 + half * (TN / 2);
#pragma unroll
    for (int c8 = 0; c8 < TN / 16; ++c8) {
      int c = half * (TN / 2) + c8 * 8;
      ushort8v vv = *(const ushort8v*)(&cst[row * TN + (c ^ swr)]);
      *(ushort8v*)(crow + c8 * 8) = vv;
    }
  }
}

// ---------------- flash attention: Q-tile 128, KV-tile 64, no-max softmax ----------------
__global__ __launch_bounds__(256) void k_flash(const ushort* __restrict__ qkv,
                                               ushort* __restrict__ ao) {
  __shared__ ushort Ks[64][64];
  __shared__ ushort Vt[64][64];
  __shared__ ushort Ps[4][32][64];
  const int LD = 2304;
  int bidl = blockIdx.y * gridDim.x + blockIdx.x;   // grid 8 x 96 = 768
  int tid = (bidl & 7) * 96 + (bidl >> 3);
  int qt = tid & 7;
  int bh = tid >> 3;
  int h = bh % HH, b = bh / HH;
  int t = threadIdx.x, w = t >> 6, l = t & 63;
  int lr = l & 15, lg = l >> 4;
  int sw = (l & 7) << 3;
  int q0 = qt * 128;
  const ushort* qbase = qkv + (size_t)(b * SS) * LD + h * 64;
  const ushort* kbase = qbase + 768;
  const ushort* vbase = qbase + 1536;
  short8v qf[2][2];
#pragma unroll
  for (int qg = 0; qg < 2; ++qg) {
    const ushort* qrow = qbase + (size_t)(q0 + w * 32 + qg * 16 + lr) * LD + lg * 8;
    qf[qg][0] = *(const short8v*)(qrow);
    qf[qg][1] = *(const short8v*)(qrow + 32);
  }
  const float CEXP = 0.125f * 1.44269504f;
  float l_run[2] = {0.f, 0.f};
  f32x4 o_acc[2][4] = {};
  int krow_ = w * 16 + (l >> 3);
  int kcol_ = ((l & 7) * 8) ^ ((krow_ & 7) << 3);
  const ushort* kg = kbase + (size_t)krow_ * LD + kcol_;
  ushort* kl = &Ks[w * 16][0];
  int d_ = t & 7;
  int dk0 = d_ * 8;
  int kv2 = (t >> 3) * 2;
  for (int kt = 0; kt < 16; ++kt) {
    int kv0 = kt * 64;
    const ushort* vr0 = vbase + (size_t)(kv0 + kv2) * LD + dk0;
    ushort8v v0 = *(const ushort8v*)(vr0);
    ushort8v v1 = *(const ushort8v*)(vr0 + LD);
    __syncthreads();
    gload16(kg + (size_t)kv0 * LD, kl);
    gload16(kg + (size_t)(kv0 + 8) * LD, kl + 512);
#pragma unroll
    for (int i = 0; i < 8; ++i) {
      unsigned int pack = (unsigned int)v0[i] | ((unsigned int)v1[i] << 16);
      *(unsigned int*)(&Vt[dk0 + i][kv2 ^ (((i ^ d_) & 7) << 3)]) = pack;
    }
    __syncthreads();
    short8v kf[4][2];
#pragma unroll
    for (int mi = 0; mi < 4; ++mi) {
      int kvr = mi * 16 + lr;
      kf[mi][0] = *(const short8v*)(&Ks[kvr][(lg * 8) ^ sw]);
      kf[mi][1] = *(const short8v*)(&Ks[kvr][(32 + lg * 8) ^ sw]);
    }
    f32x4 s[2][4] = {};
    __builtin_amdgcn_s_setprio(1);
#pragma unroll
    for (int mi = 0; mi < 4; ++mi)
#pragma unroll
      for (int qg = 0; qg < 2; ++qg) {
        s[qg][mi] = __builtin_amdgcn_mfma_f32_16x16x32_bf16(kf[mi][0], qf[qg][0], s[qg][mi], 0, 0, 0);
        s[qg][mi] = __builtin_amdgcn_mfma_f32_16x16x32_bf16(kf[mi][1], qf[qg][1], s[qg][mi], 0, 0, 0);
      }
    __builtin_amdgcn_s_setprio(0);
#pragma unroll
    for (int qg = 0; qg < 2; ++qg) {
      float psum = 0.f;
#pragma unroll
      for (int mi = 0; mi < 4; ++mi) {
        float p0 = exp2f(s[qg][mi][0] * CEXP);
        float p1 = exp2f(s[qg][mi][1] * CEXP);
        float p2 = exp2f(s[qg][mi][2] * CEXP);
        float p3 = exp2f(s[qg][mi][3] * CEXP);
        psum += (p0 + p1) + (p2 + p3);
        uint2v pp;
        pp.x = pack_bf2(p0, p1);
        pp.y = pack_bf2(p2, p3);
        *(uint2v*)(&Ps[w][qg * 16 + lr][(mi * 16 + lg * 4) ^ ((lr & 7) << 3)]) = pp;
      }
      psum += __shfl_xor(psum, 16);
      psum += __shfl_xor(psum, 32);
      l_run[qg] += psum;
    }
#pragma unroll
    for (int ks = 0; ks < 2; ++ks) {
      short8v pf[2];
      pf[0] = *(const short8v*)(&Ps[w][lr][(ks * 32 + lg * 8) ^ sw]);
      pf[1] = *(const short8v*)(&Ps[w][16 + lr][(ks * 32 + lg * 8) ^ sw]);
      short8v vf[4];
#pragma unroll
      for (int mi = 0; mi < 4; ++mi) {
        int swz = ((lr & 7) ^ (mi * 2 + (lr >> 3))) & 7;
        vf[mi] = *(const short8v*)(&Vt[mi * 16 + lr][(ks * 32 + lg * 8) ^ (swz << 3)]);
      }
      __builtin_amdgcn_s_setprio(1);
#pragma unroll
      for (int mi = 0; mi < 4; ++mi)
#pragma unroll
        for (int qg = 0; qg < 2; ++qg)
          o_acc[qg][mi] = __builtin_amdgcn_mfma_f32_16x16x32_bf16(vf[mi], pf[qg], o_acc[qg][mi], 0, 0, 0);
      __builtin_amdgcn_s_setprio(0);
    }
  }
#pragma unroll
  for (int qg = 0; qg < 2; ++qg) {
    float invl = 1.f / l_run[qg];
    ushort* orow = ao + (size_t)(b * SS + q0 + w * 32 + qg * 16 + lr) * DD + h * 64;
#pragma unroll
    for (int mi = 0; mi < 4; ++mi) {
      ushort4v o;
#pragma unroll
      for (int i = 0; i < 4; ++i) o[i] = f2bf(o_acc[qg][mi][i] * invl);
      *(ushort4v*)(orow + mi * 16 + lg * 4) = o;
    }
  }
}

// ---------------- residual add + layernorm ----------------
__global__ __launch_bounds__(256) void k_addln(float* __restrict__ x,
                                               ushort* __restrict__ xb,
                                               const ushort* __restrict__ y,
                                               const float* __restrict__ sc,
                                               const float* __restrict__ bi) {
  __shared__ float red[4];
  int row = blockIdx.x, t = threadIdx.x;
  float* xr = x + (size_t)row * DD;
  ushort* xbr = xb + (size_t)row * DD;
  const ushort* yr = y + (size_t)row * DD;
  float vals[3];
  float s = 0.f;
#pragma unroll
  for (int i = 0; i < 3; ++i) {
    float vv = xr[t + 256 * i] + bf2f(yr[t + 256 * i]);
    vals[i] = vv;
    s += vv;
  }
  float mu = block_sum(s, red) * (1.f / 768.f);
  float vs = 0.f;
#pragma unroll
  for (int i = 0; i < 3; ++i) {
    float c = vals[i] - mu;
    vs += c * c;
  }
  float rstd = rsqrtf(block_sum(vs, red) * (1.f / 768.f) + 1e-5f);
#pragma unroll
  for (int i = 0; i < 3; ++i) {
    int d = t + 256 * i;
    float o = (vals[i] - mu) * rstd * sc[d] + bi[d];
    xr[d] = o;
    xbr[d] = f2bf(o);
  }
}

// ---------------- mean pool + classifier ----------------
__global__ __launch_bounds__(256) void k_pool(const float* __restrict__ x,
                                              float* __restrict__ pooled) {
  int b = blockIdx.x, chunk = blockIdx.y, t = threadIdx.x;
  float a0 = 0, a1 = 0, a2 = 0;
  for (int s2 = chunk * 128; s2 < chunk * 128 + 128; ++s2) {
    const float* xr = x + (size_t)(b * SS + s2) * DD;
    a0 += xr[t]; a1 += xr[t + 256]; a2 += xr[t + 512];
  }
  atomicAdd(&pooled[b * DD + t], a0 * (1.f / 1024.f));
  atomicAdd(&pooled[b * DD + t + 256], a1 * (1.f / 1024.f));
  atomicAdd(&pooled[b * DD + t + 512], a2 * (1.f / 1024.f));
}

__global__ __launch_bounds__(64) void k_cls(const float* __restrict__ pooled,
                                            const float* __restrict__ Wc,
                                            const float* __restrict__ bc,
                                            float* __restrict__ out) {
  int idx = blockIdx.x;
  int b = idx / CC, c = idx % CC;
  int t = threadIdx.x;
  float acc = 0.f;
  for (int d0 = t; d0 < DD; d0 += 64) acc = fmaf(pooled[b * DD + d0], Wc[d0 * CC + c], acc);
  acc = wave_sum(acc);
  if (t == 0) out[b * CC + c] = acc + bc[c];
}

extern "C" void kernel_launch(void* const* d_in, const int* in_sizes, int n_in,
                              void* d_out, int out_size, void* d_ws, size_t ws_size,
                              hipStream_t stream) {
  (void)in_sizes; (void)n_in; (void)out_size; (void)ws_size;
  const int* tokens = (const int*)d_in[0];
  const float* emb = (const float*)d_in[1];
  const float* Wq = (const float*)d_in[2];
  const float* Wk = (const float*)d_in[3];
  const float* Wv = (const float*)d_in[4];
  const float* Wo = (const float*)d_in[5];
  const float* W1 = (const float*)d_in[6];
  const float* W2 = (const float*)d_in[7];
  const float* l1s = (const float*)d_in[8];
  const float* l1b = (const float*)d_in[9];
  const float* l2s = (const float*)d_in[10];
  const float* l2b = (const float*)d_in[11];
  const float* Wc = (const float*)d_in[12];
  const float* bc = (const float*)d_in[13];
  float* out = (float*)d_out;

  char* p = (char*)d_ws;
  float* x = (float*)p;                 p += (size_t)BS_ * DD * 4;
  ushort* xb = (ushort*)p;              p += (size_t)BS_ * DD * 2;
  ushort* qkvb = (ushort*)p;            // [8192][2304]
  ushort* hb = (ushort*)p;              // [8192][3072] overlay
  ushort* ao = (ushort*)(p + (size_t)BS_ * 2304 * 2);
  p += (size_t)BS_ * FF * 2;
  ushort* yb = (ushort*)p;              p += (size_t)BS_ * DD * 2;
  ushort* wt = (ushort*)p;              p += (size_t)(2304 * 768 + 768 * 768 + 3072 * 768 + 768 * 3072) * 2;
  float* pooled = (float*)p;

  ushort* wqkv_t = wt;                        // [2304][768]
  ushort* wo_t = wqkv_t + 2304 * 768;         // [768][768]
  ushort* w1_t = wo_t + 768 * 768;            // [3072][768]
  ushort* w2_t = w1_t + 3072 * 768;           // [768][3072]

  k_embed<<<BS_, 256, 0, stream>>>(tokens, emb, x, xb);

  for (int l = 0; l < LL; ++l) {
    k_transpose_all<<<6912, 256, 0, stream>>>(
        Wq + (size_t)l * DD * DD, Wk + (size_t)l * DD * DD,
        Wv + (size_t)l * DD * DD, Wo + (size_t)l * DD * DD,
        W1 + (size_t)l * DD * FF, W2 + (size_t)l * FF * DD,
        wqkv_t, wo_t, w1_t, w2_t);

    k_gemm_db<0, 128><<<dim3(2304 / 128, BS_ / 128), 256, 0, stream>>>(xb, wqkv_t, qkvb, BS_, 2304, DD);
    k_flash<<<dim3(SS / 128, BB * HH), 256, 0, stream>>>(qkvb, ao);
    k_gemm_db<0, 64><<<dim3(DD / 64, BS_ / 128), 256, 0, stream>>>(ao, wo_t, yb, BS_, DD, DD);
    k_addln<<<BS_, 256, 0, stream>>>(x, xb, yb, l1s + l * DD, l1b + l * DD);
    k_gemm_db<1, 128><<<dim3(FF / 128, BS_ / 128), 256, 0, stream>>>(xb, w1_t, hb, BS_, FF, DD);
    k_gemm_db<0, 64><<<dim3(DD / 64, BS_ / 128), 256, 0, stream>>>(hb, w2_t, yb, BS_, DD, FF);
    k_addln<<<BS_, 256, 0, stream>>>(x, xb, yb, l2s + l * DD, l2b + l * DD);
  }

  hipMemsetAsync(pooled, 0, (size_t)BB * DD * sizeof(float), stream);
  k_pool<<<dim3(BB, 8), 256, 0, stream>>>(x, pooled);
  k_cls<<<BB * CC, 64, 0, stream>>>(pooled, Wc, bc, out);
}